// Round 11
// baseline (98.905 us; speedup 1.0000x reference)
//
#include <hip/hip_runtime.h>
#include <math.h>

#define BB 32
#define CC 384
#define HH 56
#define WW 56
#define HWSZ (HH*WW)          // 3136
#define EPSF 1e-6f

typedef float float2v __attribute__((ext_vector_type(2)));
typedef float floatx4 __attribute__((ext_vector_type(4)));

// DPP lane-shift within 16-lane rows, zero-fill at row edges (bound_ctrl).
__device__ __forceinline__ float dpp_shr1(float v) {   // lane s gets lane s-1's v; s==0 -> 0
    return __int_as_float(__builtin_amdgcn_update_dpp(
        0, __float_as_int(v), 0x111, 0xF, 0xF, true));
}
__device__ __forceinline__ float dpp_shl1(float v) {   // lane s gets lane s+1's v; s==15 -> 0
    return __int_as_float(__builtin_amdgcn_update_dpp(
        0, __float_as_int(v), 0x101, 0xF, 0xF, true));
}

// ---------------- kernel 1: per-(b,c) mean + max over H*W (+ zero page init) ----------------
__global__ __launch_bounds__(256) void pool_kernel(const float* __restrict__ x,
                                                   float* __restrict__ xavg,
                                                   float* __restrict__ xmax,
                                                   float* __restrict__ zp) {
    int plane = blockIdx.x;                       // b*C + c
    const float4* xp = (const float4*)(x + (size_t)plane * HWSZ);
    int t = threadIdx.x;
    if (blockIdx.x == 0 && t < 16) zp[t] = 0.f;   // zero page for conv boundary loads
    float s = 0.f, m = -INFINITY;
    for (int i = t; i < HWSZ/4; i += 256) {       // 784 float4
        float4 v = xp[i];
        s += v.x + v.y + v.z + v.w;
        m = fmaxf(m, fmaxf(fmaxf(v.x, v.y), fmaxf(v.z, v.w)));
    }
    for (int off = 32; off; off >>= 1) {
        s += __shfl_down(s, off, 64);
        m = fmaxf(m, __shfl_down(m, off, 64));
    }
    __shared__ float ss[4], sm[4];
    int wid = t >> 6;
    if ((t & 63) == 0) { ss[wid] = s; sm[wid] = m; }
    __syncthreads();
    if (t == 0) {
        s = ss[0] + ss[1] + ss[2] + ss[3];
        m = fmaxf(fmaxf(sm[0], sm[1]), fmaxf(sm[2], sm[3]));
        xavg[plane] = s * (1.0f / HWSZ);
        xmax[plane] = m;
    }
}

// ---------------- kernel 2: GEMVs + GELU + Gx (parallel) ----------------
__global__ __launch_bounds__(256) void gemv_kernel(
        const float* __restrict__ xavg, const float* __restrict__ xmax,
        const float* __restrict__ w_avg, const float* __restrict__ b_avg,
        const float* __restrict__ w_max, const float* __restrict__ b_max,
        const float* __restrict__ w_mix,
        float* __restrict__ xw, float* __restrict__ Gx, float* __restrict__ partG) {
    int blk = blockIdx.x;
    int b  = blk / 6;
    int cg = blk - b*6;
    int t  = threadIdx.x;
    int ch = cg*64 + (t >> 2);           // output channel
    int kl = t & 3;                      // k-split lane

    const float4* wa = (const float4*)(w_avg + (size_t)ch * CC) + kl*24;
    const float4* wm = (const float4*)(w_max + (size_t)ch * CC) + kl*24;
    const float4* xa = (const float4*)(xavg + (size_t)b * CC) + kl*24;
    const float4* xm = (const float4*)(xmax + (size_t)b * CC) + kl*24;

    float acc = 0.f;
    #pragma unroll 4
    for (int q = 0; q < 24; ++q) {
        float4 a4 = wa[q], v4 = xa[q];
        acc += a4.x*v4.x + a4.y*v4.y + a4.z*v4.z + a4.w*v4.w;
    }
    #pragma unroll 4
    for (int q = 0; q < 24; ++q) {
        float4 m4 = wm[q], v4 = xm[q];
        acc += m4.x*v4.x + m4.y*v4.y + m4.z*v4.z + m4.w*v4.w;
    }
    acc += __shfl_xor(acc, 1);
    acc += __shfl_xor(acc, 2);

    float val = acc + b_avg[ch] + b_max[ch];
    float xwv = 0.5f * val * (1.0f + erff(val * 0.70710678118654752f));

    float sq = 0.f;
    const float* wr = w_mix + (size_t)ch * 49;
    #pragma unroll
    for (int i = 0; i < 13; ++i) {
        int j = kl + 4*i;
        if (j < 49) { float v = wr[j]; sq += v*v; }
    }
    sq += __shfl_xor(sq, 1);
    sq += __shfl_xor(sq, 2);
    float Gxv = fabsf(xwv) * sqrtf(sq);

    __shared__ float sg[64];
    if (kl == 0) {
        xw[b*CC + ch] = xwv;
        Gx[b*CC + ch] = Gxv;
        sg[t >> 2] = Gxv;
    }
    __syncthreads();
    if (t < 64) {
        float v = sg[t];
        for (int off = 32; off; off >>= 1) v += __shfl_down(v, off, 64);
        if (t == 0) partG[blk] = v;
    }
}

// ---------------- kernel 3: tap synthesis + direct-global depthwise 7x7 conv ----------------
// 128 threads = one plane, no LDS. Lane (s,g): 4-wide x 7-tall patch.
// Row loads issued in two batches bracketing tap synthesis (latency overlap);
// out-of-range rows / inactive lanes read a zero page (no per-element masking);
// neighbors via DPP; packed float2 FMA; non-temporal output stores (keep x in L3).
__global__ __launch_bounds__(128) void conv_kernel(const float* __restrict__ x,
                                                   const float* __restrict__ xw,
                                                   const float* __restrict__ Gx,
                                                   const float* __restrict__ partG,
                                                   const float* __restrict__ w_mix,
                                                   const float* __restrict__ gamma,
                                                   const float* __restrict__ beta,
                                                   const float* __restrict__ zp,
                                                   float* __restrict__ out) {
    int t = threadIdx.x;
    int plane = blockIdx.x;
    const float4* xp4 = (const float4*)(x + (size_t)plane * HWSZ);
    float4* op4 = (float4*)(out + (size_t)plane * HWSZ);
    const float4* zp4 = (const float4*)zp;

    int s = t & 15;                      // col quad (14 active)
    int g = (t >> 4) & 7;                // row-group 0..7
    bool active = (s < 14);
    int sc = active ? s : 13;
    int g7 = 7*g - 3;                    // first input row of this group's window

    // ---- per-ry source addresses (zero page when out of range / inactive)
    const float4* ap[13];
    #pragma unroll
    for (int i = 0; i < 13; ++i) {
        int ri = g7 + i;
        bool ok = ((unsigned)ri < 56u) && active;
        ap[i] = ok ? (xp4 + ri*14 + sc) : zp4;
    }

    // ---- batch 1: first 7 row loads (fly during tap synthesis)
    float4 pf[13];
    #pragma unroll
    for (int i = 0; i < 7; ++i) pf[i] = *ap[i];

    // ---- tap synthesis: kfv[j] = gamma[c]*xw*Nx * w_mix[c,j] + beta[c]  (wave-uniform SGPRs)
    float kfv[49];
    {
        int b = plane / CC;
        int c = plane - b*CC;
        float sG = partG[b*6+0] + partG[b*6+1] + partG[b*6+2]
                 + partG[b*6+3] + partG[b*6+4] + partG[b*6+5];
        float xwv = xw[plane];
        float Gxv = Gx[plane];
        float gam = gamma[c];
        float bet = beta[c];
        float coef = gam * xwv * (Gxv / (sG * (1.0f/CC) + EPSF));
        const float* wr = w_mix + (size_t)c * 49;
        #pragma unroll
        for (int j = 0; j < 49; ++j) {
            union { float f; int i; } u;
            u.f = coef * wr[j] + bet;
            u.i = __builtin_amdgcn_readfirstlane(u.i);
            kfv[j] = u.f;
        }
    }

    // ---- batch 2: remaining row loads (fly during first FMA rows)
    #pragma unroll
    for (int i = 7; i < 13; ++i) pf[i] = *ap[i];

    float2v acc2[7][2];
    #pragma unroll
    for (int i = 0; i < 7; ++i) {
        acc2[i][0] = (float2v){0.f, 0.f};
        acc2[i][1] = (float2v){0.f, 0.f};
    }

    // out(7g+oy, 4s+j) += k[ky][kx] * in(7g+oy+ky-3, 4s+j+kx-3)
    // w[i] = input col 4s-3+i: w[0..2] left DPP, w[3..6]=vb, w[7..9] right DPP.
    #pragma unroll
    for (int ry = 0; ry < 13; ++ry) {
        float4 vb = pf[ry];

        float w0 = dpp_shr1(vb.y);       // col 4s-3
        float w1 = dpp_shr1(vb.z);
        float w2 = dpp_shr1(vb.w);
        float w7 = dpp_shl1(vb.x);       // col 4s+4
        float w8 = dpp_shl1(vb.y);
        float w9 = dpp_shl1(vb.z);

        float2v wp[5], wq[4];
        wp[0] = (float2v){w0,   w1};
        wp[1] = (float2v){w2,   vb.x};
        wp[2] = (float2v){vb.y, vb.z};
        wp[3] = (float2v){vb.w, w7};
        wp[4] = (float2v){w8,   w9};
        wq[0] = (float2v){w1,   w2};
        wq[1] = (float2v){vb.x, vb.y};
        wq[2] = (float2v){vb.z, vb.w};
        wq[3] = (float2v){w7,   w8};

        int oy_lo = (ry - 6 > 0) ? (ry - 6) : 0;
        int oy_hi = (ry < 6) ? ry : 6;
        #pragma unroll
        for (int oy = 0; oy < 7; ++oy) {
            if (oy < oy_lo || oy > oy_hi) continue;
            int ky = ry - oy;
            #pragma unroll
            for (int kx = 0; kx < 7; ++kx) {
                float kv = kfv[ky*7 + kx];
                float2v kv2 = {kv, kv};
                float2v pa = (kx & 1) ? wq[kx >> 1]       : wp[kx >> 1];
                float2v pb = (kx & 1) ? wq[(kx >> 1) + 1] : wp[(kx >> 1) + 1];
                acc2[oy][0] = __builtin_elementwise_fma(kv2, pa, acc2[oy][0]);
                acc2[oy][1] = __builtin_elementwise_fma(kv2, pb, acc2[oy][1]);
            }
        }
    }

    if (active) {
        #pragma unroll
        for (int oy = 0; oy < 7; ++oy) {
            int orow = 7*g + oy;
            floatx4 o;
            o.x = acc2[oy][0].x; o.y = acc2[oy][0].y;
            o.z = acc2[oy][1].x; o.w = acc2[oy][1].y;
            __builtin_nontemporal_store(o, (floatx4*)&op4[orow*14 + sc]);
        }
    }
}

extern "C" void kernel_launch(void* const* d_in, const int* in_sizes, int n_in,
                              void* d_out, int out_size, void* d_ws, size_t ws_size,
                              hipStream_t stream) {
    const float* x     = (const float*)d_in[0];
    const float* w_avg = (const float*)d_in[1];
    const float* b_avg = (const float*)d_in[2];
    const float* w_max = (const float*)d_in[3];
    const float* b_max = (const float*)d_in[4];
    const float* w_mix = (const float*)d_in[5];
    const float* gamma = (const float*)d_in[6];
    const float* beta  = (const float*)d_in[7];
    float* out = (float*)d_out;

    float* ws    = (float*)d_ws;
    float* xavg  = ws;                      // B*C
    float* xmax  = ws + BB*CC;              // B*C
    float* xwbuf = ws + 2*BB*CC;            // B*C
    float* Gxbuf = ws + 3*BB*CC;            // B*C
    float* partG = ws + 4*BB*CC;            // 192
    float* zpage = ws + 4*BB*CC + 192;      // 16 floats, float4-aligned

    pool_kernel<<<BB*CC, 256, 0, stream>>>(x, xavg, xmax, zpage);
    gemv_kernel<<<BB*6, 256, 0, stream>>>(xavg, xmax, w_avg, b_avg, w_max, b_max,
                                          w_mix, xwbuf, Gxbuf, partG);
    conv_kernel<<<BB*CC, 128, 0, stream>>>(x, xwbuf, Gxbuf, partG, w_mix, gamma, beta,
                                           zpage, out);
}